// Round 3
// baseline (28.083 us; speedup 1.0000x reference)
//
#include <hip/hip_runtime.h>
#include <math.h>

using bf16x8 = __attribute__((ext_vector_type(8))) short;  // 8 bf16 in 4 VGPRs
using f32x4  = __attribute__((ext_vector_type(4))) float;

static __device__ __forceinline__ unsigned short f2bf(float f) {
    union { float f; unsigned u; } v; v.f = f;
    unsigned r = v.u + 0x7FFFu + ((v.u >> 16) & 1u);  // RNE
    return (unsigned short)(r >> 16);
}
static __device__ __forceinline__ unsigned pack2(float lo, float hi) {
    return (unsigned)f2bf(lo) | ((unsigned)f2bf(hi) << 16);
}

// ---------------- patch kernel: psi -> U psi -> |.|^2 -> PauliZ feats ----------------
// One block = 256 threads = 4 waves; each wave owns 64 consecutive global patches.
// Wave does 4 MFMA tiles of 16 patches: D[j][p] = sum_k U[j][k] psi[p][k] (K=16 pad 32).
__global__ __launch_bounds__(256) void quanv_patch(
    const float* __restrict__ x,      // [N,1,28,28]
    const float* __restrict__ U_re,   // [16,16]
    const float* __restrict__ U_im,   // [16,16]
    float* __restrict__ feats,        // [N*196,4]
    int total_patches)
{
    __shared__ uint4 psiQ[4][64][4];  // per-wave psi rows: 64B/row (k0..31 bf16), XOR-swizzled units

    const int tid  = threadIdx.x;
    const int wv   = tid >> 6;
    const int lane = tid & 63;
    int gp = blockIdx.x * 256 + tid;
    const bool valid = gp < total_patches;
    if (!valid) gp = total_patches - 1;  // clamp loads; stores guarded

    // --- A fragments of U: lane holds row=lane&15, k=(lane>>4)*8+i; zero for k>=16 ---
    bf16x8 uaRe, uaIm;
    if (lane < 32) {
        const int row = lane & 15, kb = (lane >> 4) * 8;
        const float4* pr4 = (const float4*)(U_re + row * 16 + kb);
        const float4* pi4 = (const float4*)(U_im + row * 16 + kb);
        const float4 r0 = pr4[0], r1 = pr4[1], i0 = pi4[0], i1 = pi4[1];
        uaRe[0] = (short)f2bf(r0.x); uaRe[1] = (short)f2bf(r0.y);
        uaRe[2] = (short)f2bf(r0.z); uaRe[3] = (short)f2bf(r0.w);
        uaRe[4] = (short)f2bf(r1.x); uaRe[5] = (short)f2bf(r1.y);
        uaRe[6] = (short)f2bf(r1.z); uaRe[7] = (short)f2bf(r1.w);
        uaIm[0] = (short)f2bf(i0.x); uaIm[1] = (short)f2bf(i0.y);
        uaIm[2] = (short)f2bf(i0.z); uaIm[3] = (short)f2bf(i0.w);
        uaIm[4] = (short)f2bf(i1.x); uaIm[5] = (short)f2bf(i1.y);
        uaIm[6] = (short)f2bf(i1.z); uaIm[7] = (short)f2bf(i1.w);
    } else {
        #pragma unroll
        for (int i = 0; i < 8; ++i) { uaRe[i] = 0; uaIm[i] = 0; }
    }

    // --- build psi for this lane's patch ---
    const int img = gp / 196;
    const int rem = gp - img * 196;
    const int prw = rem / 14;
    const int pcl = rem - prw * 14;
    const float* xi = x + (size_t)img * 784 + prw * 56 + pcl * 2;
    const float2 t0 = *(const float2*)xi;
    const float2 t1 = *(const float2*)(xi + 28);
    float s0, c0, s1, c1, s2, c2, s3, c3;
    __sincosf(t0.x * 0.5f, &s0, &c0);
    __sincosf(t0.y * 0.5f, &s1, &c1);
    __sincosf(t1.x * 0.5f, &s2, &c2);
    __sincosf(t1.y * 0.5f, &s3, &c3);
    const float a0 = c0 * c1, a1 = c0 * s1, a2 = s0 * c1, a3 = s0 * s1;
    const float b0 = c2 * c3, b1 = c2 * s3, b2 = s2 * c3, b3 = s2 * s3;

    uint4 lo, hi;
    lo.x = pack2(a0 * b0, a0 * b1); lo.y = pack2(a0 * b2, a0 * b3);
    lo.z = pack2(a1 * b0, a1 * b1); lo.w = pack2(a1 * b2, a1 * b3);
    hi.x = pack2(a2 * b0, a2 * b1); hi.y = pack2(a2 * b2, a2 * b3);
    hi.z = pack2(a3 * b0, a3 * b1); hi.w = pack2(a3 * b2, a3 * b3);

    const int sw_w = (lane ^ (lane >> 2)) & 3;          // XOR swizzle on 16B units
    const uint4 z4 = make_uint4(0u, 0u, 0u, 0u);
    psiQ[wv][lane][0 ^ sw_w] = lo;   // k 0..7
    psiQ[wv][lane][1 ^ sw_w] = hi;   // k 8..15
    psiQ[wv][lane][2 ^ sw_w] = z4;   // k 16..23 (pad)
    psiQ[wv][lane][3 ^ sw_w] = z4;   // k 24..31 (pad)
    __syncthreads();

    const int g    = lane >> 4;      // j-group (j = 4g + reg)
    const int cpat = lane & 15;      // this lane's patch within tile
    const int wave_base = blockIdx.x * 256 + wv * 64;

    #pragma unroll
    for (int T = 0; T < 4; ++T) {
        const int row = T * 16 + cpat;
        const int sw_r = (row ^ (row >> 2)) & 3;
        const bf16x8 bfrag = *(const bf16x8*)&psiQ[wv][row][g ^ sw_r];
        const f32x4 zacc = {0.f, 0.f, 0.f, 0.f};
        const f32x4 dre = __builtin_amdgcn_mfma_f32_16x16x32_bf16(uaRe, bfrag, zacc, 0, 0, 0);
        const f32x4 dim = __builtin_amdgcn_mfma_f32_16x16x32_bf16(uaIm, bfrag, zacc, 0, 0, 0);
        const float P0 = dre[0] * dre[0] + dim[0] * dim[0];
        const float P1 = dre[1] * dre[1] + dim[1] * dim[1];
        const float P2 = dre[2] * dre[2] + dim[2] * dim[2];
        const float P3 = dre[3] * dre[3] + dim[3] * dim[3];
        // j = 4g+r; bits: j3=g1, j2=g0, j1=r1, j0=r0. wire w <-> bit (3-w).
        float S  = P0 + P1 + P2 + P3;           // for z0,z1
        float B2 = P0 + P1 - P2 - P3;           // (-1)^{r1} -> wire2
        float B3 = P0 - P1 + P2 - P3;           // (-1)^{r0} -> wire3
        B2 += __shfl_xor(B2, 16, 64); B2 += __shfl_xor(B2, 32, 64);   // z2
        B3 += __shfl_xor(B3, 16, 64); B3 += __shfl_xor(B3, 32, 64);   // z3
        const float t16 = __shfl_xor(S, 16, 64);
        float d = (g & 1) ? (t16 - S) : (S - t16);                    // (-1)^{g0}
        const float e = S + t16;
        d += __shfl_xor(d, 32, 64);                                   // z1
        const float t32 = __shfl_xor(e, 32, 64);
        const float z0 = (g & 2) ? (t32 - e) : (e - t32);             // (-1)^{g1}
        const int sp = wave_base + T * 16 + cpat;
        if (lane < 16 && sp < total_patches) {
            *(float4*)(feats + (size_t)sp * 4) = make_float4(z0, d, B2, B3);
        }
    }
}

// ---------------- head kernel: logits + log_softmax ----------------
__global__ __launch_bounds__(64) void quanv_head(
    const float* __restrict__ feats,  // [N,784]
    const float* __restrict__ W,      // [10,784]
    const float* __restrict__ bias,   // [10]
    float* __restrict__ out)          // [N,10]
{
    const int img  = blockIdx.x;
    const int lane = threadIdx.x;
    const float* f = feats + (size_t)img * 784;
    float acc[10];
    #pragma unroll
    for (int c = 0; c < 10; ++c) acc[c] = 0.f;
    for (int i = lane; i < 784; i += 64) {
        const float fv = f[i];
        #pragma unroll
        for (int c = 0; c < 10; ++c) acc[c] = fmaf(W[c * 784 + i], fv, acc[c]);
    }
    #pragma unroll
    for (int c = 0; c < 10; ++c) {
        #pragma unroll
        for (int off = 32; off; off >>= 1) acc[c] += __shfl_down(acc[c], off, 64);
    }
    if (lane == 0) {
        float lg[10], m = -1e30f;
        #pragma unroll
        for (int c = 0; c < 10; ++c) { lg[c] = acc[c] + bias[c]; m = fmaxf(m, lg[c]); }
        float ssum = 0.f;
        #pragma unroll
        for (int c = 0; c < 10; ++c) ssum += expf(lg[c] - m);
        const float lse = m + logf(ssum);
        #pragma unroll
        for (int c = 0; c < 10; ++c) out[(size_t)img * 10 + c] = lg[c] - lse;
    }
}

// ---------------- fallback (round-1 fused, if ws too small) ----------------
__global__ __launch_bounds__(256) void quanv_fused(
    const float* __restrict__ x, const float* __restrict__ U_re,
    const float* __restrict__ U_im, const float* __restrict__ W,
    const float* __restrict__ bias, float* __restrict__ out)
{
    __shared__ float sfeat[784];
    __shared__ float swred[4][10];
    __shared__ float slog[10];
    const int img = blockIdx.x, tid = threadIdx.x;
    const float* xi = x + (size_t)img * 784;
    if (tid < 196) {
        const int pr = tid / 14, pc = tid - pr * 14;
        const float2 r0 = *(const float2*)(xi + (2 * pr) * 28 + 2 * pc);
        const float2 r1 = *(const float2*)(xi + (2 * pr + 1) * 28 + 2 * pc);
        float s0, c0, s1, c1, s2, c2, s3, c3;
        __sincosf(r0.x * 0.5f, &s0, &c0); __sincosf(r0.y * 0.5f, &s1, &c1);
        __sincosf(r1.x * 0.5f, &s2, &c2); __sincosf(r1.y * 0.5f, &s3, &c3);
        const float a0 = c0 * c1, a1 = c0 * s1, a2 = s0 * c1, a3 = s0 * s1;
        const float b0 = c2 * c3, b1 = c2 * s3, b2 = s2 * c3, b3 = s2 * s3;
        float psi[16];
        psi[0]=a0*b0; psi[1]=a0*b1; psi[2]=a0*b2; psi[3]=a0*b3;
        psi[4]=a1*b0; psi[5]=a1*b1; psi[6]=a1*b2; psi[7]=a1*b3;
        psi[8]=a2*b0; psi[9]=a2*b1; psi[10]=a2*b2; psi[11]=a2*b3;
        psi[12]=a3*b0; psi[13]=a3*b1; psi[14]=a3*b2; psi[15]=a3*b3;
        float z0=0.f,z1=0.f,z2=0.f,z3=0.f;
        #pragma unroll
        for (int j = 0; j < 16; ++j) {
            const float4* Ur = (const float4*)(U_re + j * 16);
            const float4* Ui = (const float4*)(U_im + j * 16);
            float re=0.f, im=0.f;
            #pragma unroll
            for (int q = 0; q < 4; ++q) {
                const float4 ur = Ur[q], ui = Ui[q];
                re = fmaf(ur.x, psi[q*4+0], re); re = fmaf(ur.y, psi[q*4+1], re);
                re = fmaf(ur.z, psi[q*4+2], re); re = fmaf(ur.w, psi[q*4+3], re);
                im = fmaf(ui.x, psi[q*4+0], im); im = fmaf(ui.y, psi[q*4+1], im);
                im = fmaf(ui.z, psi[q*4+2], im); im = fmaf(ui.w, psi[q*4+3], im);
            }
            const float p = re*re + im*im;
            z0 += (j & 8) ? -p : p; z1 += (j & 4) ? -p : p;
            z2 += (j & 2) ? -p : p; z3 += (j & 1) ? -p : p;
        }
        sfeat[tid*4+0]=z0; sfeat[tid*4+1]=z1; sfeat[tid*4+2]=z2; sfeat[tid*4+3]=z3;
    }
    __syncthreads();
    float acc[10];
    #pragma unroll
    for (int c = 0; c < 10; ++c) acc[c] = 0.f;
    for (int f = tid; f < 784; f += 256) {
        const float fv = sfeat[f];
        #pragma unroll
        for (int c = 0; c < 10; ++c) acc[c] = fmaf(W[c*784+f], fv, acc[c]);
    }
    #pragma unroll
    for (int c = 0; c < 10; ++c) {
        #pragma unroll
        for (int off = 32; off; off >>= 1) acc[c] += __shfl_down(acc[c], off, 64);
    }
    const int wid = tid >> 6, lane = tid & 63;
    if (lane == 0) {
        #pragma unroll
        for (int c = 0; c < 10; ++c) swred[wid][c] = acc[c];
    }
    __syncthreads();
    if (tid < 10) slog[tid] = bias[tid] + swred[0][tid] + swred[1][tid] + swred[2][tid] + swred[3][tid];
    __syncthreads();
    if (tid < 10) {
        float m = slog[0];
        #pragma unroll
        for (int i = 1; i < 10; ++i) m = fmaxf(m, slog[i]);
        float s = 0.f;
        #pragma unroll
        for (int i = 0; i < 10; ++i) s += expf(slog[i] - m);
        out[(size_t)img * 10 + tid] = slog[tid] - m - logf(s);
    }
}

extern "C" void kernel_launch(void* const* d_in, const int* in_sizes, int n_in,
                              void* d_out, int out_size, void* d_ws, size_t ws_size,
                              hipStream_t stream) {
    const float* x    = (const float*)d_in[0];
    const float* U_re = (const float*)d_in[1];
    const float* U_im = (const float*)d_in[2];
    const float* W    = (const float*)d_in[3];
    const float* bias = (const float*)d_in[4];
    float* out = (float*)d_out;
    const int n = in_sizes[0] / 784;
    const int total_patches = n * 196;
    const size_t need = (size_t)total_patches * 4 * sizeof(float);
    if (ws_size >= need) {
        float* feats = (float*)d_ws;
        const int nblk = (total_patches + 255) / 256;
        quanv_patch<<<nblk, 256, 0, stream>>>(x, U_re, U_im, feats, total_patches);
        quanv_head<<<n, 64, 0, stream>>>(feats, W, bias, out);
    } else {
        quanv_fused<<<n, 256, 0, stream>>>(x, U_re, U_im, W, bias, out);
    }
}

// Round 5
// 27.375 us; speedup vs baseline: 1.0259x; 1.0259x over previous
//
#include <hip/hip_runtime.h>
#include <math.h>

using bf16x8 = __attribute__((ext_vector_type(8))) short;  // 8 bf16 in 4 VGPRs
using f32x4  = __attribute__((ext_vector_type(4))) float;

static __device__ __forceinline__ unsigned cvt_pk_bf16(float lo, float hi) {
    unsigned r;
    asm("v_cvt_pk_bf16_f32 %0, %1, %2" : "=v"(r) : "v"(lo), "v"(hi));
    return r;
}
static __device__ __forceinline__ unsigned short f2bf(float f) {
    union { float f; unsigned u; } v; v.f = f;
    unsigned r = v.u + 0x7FFFu + ((v.u >> 16) & 1u);  // RNE
    return (unsigned short)(r >> 16);
}

#define REV_HALF 0.07957747154594767f  // 1/(4*pi): theta -> revolutions of theta/2

static __device__ __forceinline__ void sincos_half(float theta, float* s, float* c) {
#if defined(__has_builtin)
#if __has_builtin(__builtin_amdgcn_sinf) && __has_builtin(__builtin_amdgcn_cosf)
    const float r = theta * REV_HALF;
    *s = __builtin_amdgcn_sinf(r);
    *c = __builtin_amdgcn_cosf(r);
    return;
#endif
#endif
    __sincosf(theta * 0.5f, s, c);
}

// One block = one image. 4 waves; wave wv owns patch slots [wv*64, wv*64+64),
// of which only slots < 196 are real. Patch phase (verified round-3 structure):
//   psi (bf16, per-lane) -> LDS -> MFMA D1[j][p] = sum_k U[j][k] psi[p][k]
//   P = |D1re|^2+|D1im|^2 -> signed shuffle-reduce -> z0..z3 per patch -> LDS sfeat
// Head phase (verified round-1): 784x10 matvec + log_softmax.
__global__ __launch_bounds__(256) void quanv_one(
    const float* __restrict__ x,      // [N,1,28,28]
    const float* __restrict__ U_re,   // [16,16]
    const float* __restrict__ U_im,   // [16,16]
    const float* __restrict__ W,      // [10,784]
    const float* __restrict__ bias,   // [10]
    float* __restrict__ out)          // [N,10]
{
    __shared__ uint4  psiQ[4][64][4];  // per-wave psi rows: 64B/row (k0..31 bf16), XOR-swizzled
    __shared__ float4 sfeat4[196];     // z per patch
    __shared__ float  swred[4][10];
    __shared__ float  slog[10];

    const int tid  = threadIdx.x;
    const int wv   = tid >> 6;
    const int lane = tid & 63;
    const int img  = blockIdx.x;

    // --- A fragments of U: lane holds row=lane&15, k=(lane>>4)*8+i; zero for k>=16 ---
    bf16x8 uaRe, uaIm;
    if (lane < 32) {
        const int row = lane & 15, kb = (lane >> 4) * 8;
        const float4* pr4 = (const float4*)(U_re + row * 16 + kb);
        const float4* pi4 = (const float4*)(U_im + row * 16 + kb);
        const float4 r0 = pr4[0], r1 = pr4[1], i0 = pi4[0], i1 = pi4[1];
        uaRe[0] = (short)f2bf(r0.x); uaRe[1] = (short)f2bf(r0.y);
        uaRe[2] = (short)f2bf(r0.z); uaRe[3] = (short)f2bf(r0.w);
        uaRe[4] = (short)f2bf(r1.x); uaRe[5] = (short)f2bf(r1.y);
        uaRe[6] = (short)f2bf(r1.z); uaRe[7] = (short)f2bf(r1.w);
        uaIm[0] = (short)f2bf(i0.x); uaIm[1] = (short)f2bf(i0.y);
        uaIm[2] = (short)f2bf(i0.z); uaIm[3] = (short)f2bf(i0.w);
        uaIm[4] = (short)f2bf(i1.x); uaIm[5] = (short)f2bf(i1.y);
        uaIm[6] = (short)f2bf(i1.z); uaIm[7] = (short)f2bf(i1.w);
    } else {
        #pragma unroll
        for (int i = 0; i < 8; ++i) { uaRe[i] = 0; uaIm[i] = 0; }
    }

    // --- build psi for this lane's patch (clamped for slots >= 196) ---
    const int p   = (tid < 196) ? tid : 195;
    const int prw = p / 14;
    const int pcl = p - prw * 14;
    const float* xi = x + (size_t)img * 784 + prw * 56 + pcl * 2;
    const float2 t0 = *(const float2*)xi;
    const float2 t1 = *(const float2*)(xi + 28);
    float s0, c0, s1, c1, s2, c2, s3, c3;
    sincos_half(t0.x, &s0, &c0);
    sincos_half(t0.y, &s1, &c1);
    sincos_half(t1.x, &s2, &c2);
    sincos_half(t1.y, &s3, &c3);
    const float a0 = c0 * c1, a1 = c0 * s1, a2 = s0 * c1, a3 = s0 * s1;
    const float b0 = c2 * c3, b1 = c2 * s3, b2 = s2 * c3, b3 = s2 * s3;

    uint4 lo, hi;
    lo.x = cvt_pk_bf16(a0 * b0, a0 * b1); lo.y = cvt_pk_bf16(a0 * b2, a0 * b3);
    lo.z = cvt_pk_bf16(a1 * b0, a1 * b1); lo.w = cvt_pk_bf16(a1 * b2, a1 * b3);
    hi.x = cvt_pk_bf16(a2 * b0, a2 * b1); hi.y = cvt_pk_bf16(a2 * b2, a2 * b3);
    hi.z = cvt_pk_bf16(a3 * b0, a3 * b1); hi.w = cvt_pk_bf16(a3 * b2, a3 * b3);

    const int sw_w = (lane ^ (lane >> 2)) & 3;          // XOR swizzle on 16B units
    const uint4 z4 = make_uint4(0u, 0u, 0u, 0u);
    psiQ[wv][lane][0 ^ sw_w] = lo;   // k 0..7
    psiQ[wv][lane][1 ^ sw_w] = hi;   // k 8..15
    psiQ[wv][lane][2 ^ sw_w] = z4;   // k 16..23 (pad)
    psiQ[wv][lane][3 ^ sw_w] = z4;   // k 24..31 (pad)
    __syncthreads();

    const int g    = lane >> 4;      // j-group / B-frag k-group
    const int cpat = lane & 15;      // this lane's patch within tile
    const f32x4 zacc = {0.f, 0.f, 0.f, 0.f};

    #pragma unroll
    for (int T = 0; T < 4; ++T) {
        const int row = T * 16 + cpat;
        const int sw_r = (row ^ (row >> 2)) & 3;
        const bf16x8 bfrag = *(const bf16x8*)&psiQ[wv][row][g ^ sw_r];
        const f32x4 dre = __builtin_amdgcn_mfma_f32_16x16x32_bf16(uaRe, bfrag, zacc, 0, 0, 0);
        const f32x4 dim = __builtin_amdgcn_mfma_f32_16x16x32_bf16(uaIm, bfrag, zacc, 0, 0, 0);
        const float P0 = dre[0] * dre[0] + dim[0] * dim[0];
        const float P1 = dre[1] * dre[1] + dim[1] * dim[1];
        const float P2 = dre[2] * dre[2] + dim[2] * dim[2];
        const float P3 = dre[3] * dre[3] + dim[3] * dim[3];
        // j = 4g+r; bits: j3=g1, j2=g0, j1=r1, j0=r0. wire w <-> bit (3-w).
        float S  = P0 + P1 + P2 + P3;           // for z0,z1
        float B2 = P0 + P1 - P2 - P3;           // (-1)^{r1} -> wire2
        float B3 = P0 - P1 + P2 - P3;           // (-1)^{r0} -> wire3
        B2 += __shfl_xor(B2, 16, 64); B2 += __shfl_xor(B2, 32, 64);   // z2
        B3 += __shfl_xor(B3, 16, 64); B3 += __shfl_xor(B3, 32, 64);   // z3
        const float t16 = __shfl_xor(S, 16, 64);
        float d = (g & 1) ? (t16 - S) : (S - t16);                    // (-1)^{g0}
        const float e = S + t16;
        d += __shfl_xor(d, 32, 64);                                   // z1
        const float t32 = __shfl_xor(e, 32, 64);
        const float z0 = (g & 2) ? (t32 - e) : (e - t32);             // (-1)^{g1}
        const int sp = wv * 64 + T * 16 + cpat;
        if (lane < 16 && sp < 196) {
            sfeat4[sp] = make_float4(z0, d, B2, B3);
        }
    }
    __syncthreads();

    // ---------- head: logits + log_softmax ----------
    const float* sfeat = (const float*)sfeat4;
    float acc[10];
    #pragma unroll
    for (int c = 0; c < 10; ++c) acc[c] = 0.f;
    for (int f = tid; f < 784; f += 256) {
        const float fv = sfeat[f];
        #pragma unroll
        for (int c = 0; c < 10; ++c) acc[c] = fmaf(W[c * 784 + f], fv, acc[c]);
    }
    #pragma unroll
    for (int c = 0; c < 10; ++c) {
        #pragma unroll
        for (int off = 32; off; off >>= 1) acc[c] += __shfl_down(acc[c], off, 64);
    }
    if (lane == 0) {
        #pragma unroll
        for (int c = 0; c < 10; ++c) swred[wv][c] = acc[c];
    }
    __syncthreads();
    if (tid < 10) slog[tid] = bias[tid] + swred[0][tid] + swred[1][tid] + swred[2][tid] + swred[3][tid];
    __syncthreads();
    if (tid < 10) {
        float m = slog[0];
        #pragma unroll
        for (int i = 1; i < 10; ++i) m = fmaxf(m, slog[i]);
        float s = 0.f;
        #pragma unroll
        for (int i = 0; i < 10; ++i) s += expf(slog[i] - m);
        out[(size_t)img * 10 + tid] = slog[tid] - m - logf(s);
    }
}

extern "C" void kernel_launch(void* const* d_in, const int* in_sizes, int n_in,
                              void* d_out, int out_size, void* d_ws, size_t ws_size,
                              hipStream_t stream) {
    const float* x    = (const float*)d_in[0];
    const float* U_re = (const float*)d_in[1];
    const float* U_im = (const float*)d_in[2];
    const float* W    = (const float*)d_in[3];
    const float* bias = (const float*)d_in[4];
    float* out = (float*)d_out;
    const int n = in_sizes[0] / 784;  // 4096 images
    quanv_one<<<n, 256, 0, stream>>>(x, U_re, U_im, W, bias, out);
}

// Round 6
// 21.140 us; speedup vs baseline: 1.3285x; 1.2949x over previous
//
#include <hip/hip_runtime.h>
#include <math.h>

using bf16x8 = __attribute__((ext_vector_type(8))) short;  // 8 bf16 in 4 VGPRs
using f32x4  = __attribute__((ext_vector_type(4))) float;

static __device__ __forceinline__ unsigned cvt_pk_bf16(float lo, float hi) {
    unsigned r;
    asm("v_cvt_pk_bf16_f32 %0, %1, %2" : "=v"(r) : "v"(lo), "v"(hi));
    return r;
}
static __device__ __forceinline__ unsigned short f2bf(float f) {
    union { float f; unsigned u; } v; v.f = f;
    unsigned r = v.u + 0x7FFFu + ((v.u >> 16) & 1u);  // RNE
    return (unsigned short)(r >> 16);
}

#define REV_HALF 0.07957747154594767f  // 1/(4*pi): theta -> revolutions of theta/2

static __device__ __forceinline__ void sincos_half(float theta, float* s, float* c) {
    const float r = theta * REV_HALF;
    *s = __builtin_amdgcn_sinf(r);
    *c = __builtin_amdgcn_cosf(r);
}

// One block = one image; 4 waves.
// Patch phase (verified R3/R5): psi(bf16)->LDS->MFMA D1=U*psi -> P=|.|^2 -> Walsh
// shuffle-reduce -> z per patch -> LDS sfeat.
// Head phase: wave wv owns classes [cstart[wv],cstart[wv+1]) over all 784 feats;
// butterfly-reduce per class; softmax parallel on lanes 0..9 of wave 0.
__global__ __launch_bounds__(256) void quanv_one(
    const float* __restrict__ x,      // [N,1,28,28]
    const float* __restrict__ U_re,   // [16,16]
    const float* __restrict__ U_im,   // [16,16]
    const float* __restrict__ W,      // [10,784]
    const float* __restrict__ bias,   // [10]
    float* __restrict__ out)          // [N,10]
{
    __shared__ uint4  psiQ[4][64][4];  // per-wave psi rows: 64B/row (k0..31 bf16), XOR-swizzled
    __shared__ float4 sfeat4[196];     // z per patch
    __shared__ float  slog[10];

    const int tid  = threadIdx.x;
    const int wv   = tid >> 6;
    const int lane = tid & 63;
    const int img  = blockIdx.x;

    // --- A fragments of U: lane holds row=lane&15, k=(lane>>4)*8+i; zero for k>=16 ---
    bf16x8 uaRe, uaIm;
    if (lane < 32) {
        const int row = lane & 15, kb = (lane >> 4) * 8;
        const float4* pr4 = (const float4*)(U_re + row * 16 + kb);
        const float4* pi4 = (const float4*)(U_im + row * 16 + kb);
        const float4 r0 = pr4[0], r1 = pr4[1], i0 = pi4[0], i1 = pi4[1];
        uaRe[0] = (short)f2bf(r0.x); uaRe[1] = (short)f2bf(r0.y);
        uaRe[2] = (short)f2bf(r0.z); uaRe[3] = (short)f2bf(r0.w);
        uaRe[4] = (short)f2bf(r1.x); uaRe[5] = (short)f2bf(r1.y);
        uaRe[6] = (short)f2bf(r1.z); uaRe[7] = (short)f2bf(r1.w);
        uaIm[0] = (short)f2bf(i0.x); uaIm[1] = (short)f2bf(i0.y);
        uaIm[2] = (short)f2bf(i0.z); uaIm[3] = (short)f2bf(i0.w);
        uaIm[4] = (short)f2bf(i1.x); uaIm[5] = (short)f2bf(i1.y);
        uaIm[6] = (short)f2bf(i1.z); uaIm[7] = (short)f2bf(i1.w);
    } else {
        #pragma unroll
        for (int i = 0; i < 8; ++i) { uaRe[i] = 0; uaIm[i] = 0; }
    }

    // --- build psi for this lane's patch (clamped for slots >= 196) ---
    const int p   = (tid < 196) ? tid : 195;
    const int prw = p / 14;
    const int pcl = p - prw * 14;
    const float* xi = x + (size_t)img * 784 + prw * 56 + pcl * 2;
    const float2 t0 = *(const float2*)xi;
    const float2 t1 = *(const float2*)(xi + 28);
    float s0, c0, s1, c1, s2, c2, s3, c3;
    sincos_half(t0.x, &s0, &c0);
    sincos_half(t0.y, &s1, &c1);
    sincos_half(t1.x, &s2, &c2);
    sincos_half(t1.y, &s3, &c3);
    const float a0 = c0 * c1, a1 = c0 * s1, a2 = s0 * c1, a3 = s0 * s1;
    const float b0 = c2 * c3, b1 = c2 * s3, b2 = s2 * c3, b3 = s2 * s3;

    uint4 lo, hi;
    lo.x = cvt_pk_bf16(a0 * b0, a0 * b1); lo.y = cvt_pk_bf16(a0 * b2, a0 * b3);
    lo.z = cvt_pk_bf16(a1 * b0, a1 * b1); lo.w = cvt_pk_bf16(a1 * b2, a1 * b3);
    hi.x = cvt_pk_bf16(a2 * b0, a2 * b1); hi.y = cvt_pk_bf16(a2 * b2, a2 * b3);
    hi.z = cvt_pk_bf16(a3 * b0, a3 * b1); hi.w = cvt_pk_bf16(a3 * b2, a3 * b3);

    const int sw_w = (lane ^ (lane >> 2)) & 3;          // XOR swizzle on 16B units
    const uint4 z4 = make_uint4(0u, 0u, 0u, 0u);
    psiQ[wv][lane][0 ^ sw_w] = lo;   // k 0..7
    psiQ[wv][lane][1 ^ sw_w] = hi;   // k 8..15
    psiQ[wv][lane][2 ^ sw_w] = z4;   // k 16..23 (pad)
    psiQ[wv][lane][3 ^ sw_w] = z4;   // k 24..31 (pad)
    __syncthreads();

    const int g    = lane >> 4;      // j-group / B-frag k-group
    const int cpat = lane & 15;      // this lane's patch within tile
    const f32x4 zacc = {0.f, 0.f, 0.f, 0.f};

    #pragma unroll
    for (int T = 0; T < 4; ++T) {
        const int row = T * 16 + cpat;
        const int sw_r = (row ^ (row >> 2)) & 3;
        const bf16x8 bfrag = *(const bf16x8*)&psiQ[wv][row][g ^ sw_r];
        const f32x4 dre = __builtin_amdgcn_mfma_f32_16x16x32_bf16(uaRe, bfrag, zacc, 0, 0, 0);
        const f32x4 dim = __builtin_amdgcn_mfma_f32_16x16x32_bf16(uaIm, bfrag, zacc, 0, 0, 0);
        const float P0 = dre[0] * dre[0] + dim[0] * dim[0];
        const float P1 = dre[1] * dre[1] + dim[1] * dim[1];
        const float P2 = dre[2] * dre[2] + dim[2] * dim[2];
        const float P3 = dre[3] * dre[3] + dim[3] * dim[3];
        // j = 4g+r; bits: j3=g1, j2=g0, j1=r1, j0=r0. wire w <-> bit (3-w).
        float S  = P0 + P1 + P2 + P3;           // for z0,z1
        float B2 = P0 + P1 - P2 - P3;           // (-1)^{r1} -> wire2
        float B3 = P0 - P1 + P2 - P3;           // (-1)^{r0} -> wire3
        B2 += __shfl_xor(B2, 16, 64); B2 += __shfl_xor(B2, 32, 64);   // z2
        B3 += __shfl_xor(B3, 16, 64); B3 += __shfl_xor(B3, 32, 64);   // z3
        const float t16 = __shfl_xor(S, 16, 64);
        float d = (g & 1) ? (t16 - S) : (S - t16);                    // (-1)^{g0}
        const float e = S + t16;
        d += __shfl_xor(d, 32, 64);                                   // z1
        const float t32 = __shfl_xor(e, 32, 64);
        const float z0 = (g & 2) ? (t32 - e) : (e - t32);             // (-1)^{g1}
        const int sp = wv * 64 + T * 16 + cpat;
        if (lane < 16 && sp < 196) {
            sfeat4[sp] = make_float4(z0, d, B2, B3);
        }
    }
    __syncthreads();

    // ---------- head: wave wv owns classes [cstart[wv], cstart[wv+1]) ----------
    const float* sfeat = (const float*)sfeat4;
    const int cs = (wv == 0) ? 0 : (wv == 1) ? 3 : (wv == 2) ? 6 : 8;
    const int nc = (wv <= 1) ? 3 : 2;
    float acc0 = 0.f, acc1 = 0.f, acc2 = 0.f;
    #pragma unroll
    for (int i = 0; i < 12; ++i) {
        const int f = i * 64 + lane;
        const float fv = sfeat[f];
        acc0 = fmaf(W[(cs + 0) * 784 + f], fv, acc0);
        acc1 = fmaf(W[(cs + 1) * 784 + f], fv, acc1);
        if (nc > 2) acc2 = fmaf(W[(cs + 2) * 784 + f], fv, acc2);
    }
    if (lane < 16) {
        const int f = 768 + lane;
        const float fv = sfeat[f];
        acc0 = fmaf(W[(cs + 0) * 784 + f], fv, acc0);
        acc1 = fmaf(W[(cs + 1) * 784 + f], fv, acc1);
        if (nc > 2) acc2 = fmaf(W[(cs + 2) * 784 + f], fv, acc2);
    }
    #pragma unroll
    for (int off = 32; off; off >>= 1) {
        acc0 += __shfl_xor(acc0, off, 64);
        acc1 += __shfl_xor(acc1, off, 64);
        acc2 += __shfl_xor(acc2, off, 64);
    }
    if (lane == 0) {
        slog[cs + 0] = acc0 + bias[cs + 0];
        slog[cs + 1] = acc1 + bias[cs + 1];
        if (nc > 2) slog[cs + 2] = acc2 + bias[cs + 2];
    }
    __syncthreads();

    // ---------- softmax: lanes 0..15 of wave 0 (10 real) ----------
    if (wv == 0 && lane < 16) {
        const float lg = (lane < 10) ? slog[lane] : -1e30f;
        float m = lg;
        #pragma unroll
        for (int off = 8; off; off >>= 1) m = fmaxf(m, __shfl_xor(m, off, 64));
        float e = (lane < 10) ? __expf(lg - m) : 0.f;
        float s = e;
        #pragma unroll
        for (int off = 8; off; off >>= 1) s += __shfl_xor(s, off, 64);
        if (lane < 10) out[(size_t)img * 10 + lane] = lg - m - __logf(s);
    }
}

extern "C" void kernel_launch(void* const* d_in, const int* in_sizes, int n_in,
                              void* d_out, int out_size, void* d_ws, size_t ws_size,
                              hipStream_t stream) {
    const float* x    = (const float*)d_in[0];
    const float* U_re = (const float*)d_in[1];
    const float* U_im = (const float*)d_in[2];
    const float* W    = (const float*)d_in[3];
    const float* bias = (const float*)d_in[4];
    float* out = (float*)d_out;
    const int n = in_sizes[0] / 784;  // 4096 images
    quanv_one<<<n, 256, 0, stream>>>(x, U_re, U_im, W, bias, out);
}

// Round 7
// 18.302 us; speedup vs baseline: 1.5344x; 1.1551x over previous
//
#include <hip/hip_runtime.h>
#include <math.h>

using bf16x8 = __attribute__((ext_vector_type(8))) short;   // 8 bf16 in 4 VGPRs
using f32x16 = __attribute__((ext_vector_type(16))) float;  // 32x32 MFMA acc

static __device__ __forceinline__ unsigned cvt_pk_bf16(float lo, float hi) {
    unsigned r;
    asm("v_cvt_pk_bf16_f32 %0, %1, %2" : "=v"(r) : "v"(lo), "v"(hi));
    return r;
}

#define REV_HALF 0.07957747154594767f  // 1/(4*pi): theta -> revolutions of theta/2

// One block = one image; 4 waves; wave wv owns patches [wv*64, wv*64+64).
// Patch phase: per-lane psi (bf16 halves) -> shfl redistribution -> ONE
// mfma_f32_32x32x16_bf16 per 32-patch tile with A=[U_re;U_im] stacked (32x16,
// K exact) -> P=Re^2+Im^2 in-register -> 8-point Walsh (j2=hi cross-lane) -> z.
// Head phase (R6-verified): wave wv owns 2-3 classes; butterfly reduce; wave-0
// parallel softmax.
__global__ __launch_bounds__(256) void quanv_one(
    const float* __restrict__ x,      // [N,1,28,28]
    const float* __restrict__ U_re,   // [16,16]
    const float* __restrict__ U_im,   // [16,16]
    const float* __restrict__ W,      // [10,784]
    const float* __restrict__ bias,   // [10]
    float* __restrict__ out)          // [N,10]
{
    __shared__ float4 sfeat4[196];    // z per patch
    __shared__ float  slog[10];

    const int tid  = threadIdx.x;
    const int wv   = tid >> 6;
    const int lane = tid & 63;
    const int l31  = lane & 31;
    const int hi   = lane >> 5;       // k-half / j2 bit
    const int img  = blockIdx.x;

    // ---- A fragment: stacked 32x16 [U_re; U_im]; row=lane&31, k=hi*8+i ----
    const float* Urow = (l31 < 16) ? (U_re + l31 * 16) : (U_im + (l31 - 16) * 16);
    const float4 uf0 = *(const float4*)(Urow + hi * 8);
    const float4 uf1 = *(const float4*)(Urow + hi * 8 + 4);
    union { unsigned u[4]; bf16x8 v; } ua;
    ua.u[0] = cvt_pk_bf16(uf0.x, uf0.y);
    ua.u[1] = cvt_pk_bf16(uf0.z, uf0.w);
    ua.u[2] = cvt_pk_bf16(uf1.x, uf1.y);
    ua.u[3] = cvt_pk_bf16(uf1.z, uf1.w);

    // ---- psi for this lane's own patch (clamped for slots >= 196) ----
    const int p   = (tid < 196) ? tid : 195;
    const int prw = p / 14;
    const int pcl = p - prw * 14;
    const float* xi = x + (size_t)img * 784 + prw * 56 + pcl * 2;
    const float2 t0 = *(const float2*)xi;
    const float2 t1 = *(const float2*)(xi + 28);
    const float r0 = t0.x * REV_HALF, r1 = t0.y * REV_HALF;
    const float r2 = t1.x * REV_HALF, r3 = t1.y * REV_HALF;
    const float s0 = __builtin_amdgcn_sinf(r0), c0 = __builtin_amdgcn_cosf(r0);
    const float s1 = __builtin_amdgcn_sinf(r1), c1 = __builtin_amdgcn_cosf(r1);
    const float s2 = __builtin_amdgcn_sinf(r2), c2 = __builtin_amdgcn_cosf(r2);
    const float s3 = __builtin_amdgcn_sinf(r3), c3 = __builtin_amdgcn_cosf(r3);
    const float a0 = c0 * c1, a1 = c0 * s1, a2 = s0 * c1, a3 = s0 * s1;
    const float b0 = c2 * c3, b1 = c2 * s3, b2 = s2 * c3, b3 = s2 * s3;

    // psi halves: pL = k0..7, pH = k8..15 (bf16 pairs)
    unsigned pL[4], pH[4];
    pL[0] = cvt_pk_bf16(a0 * b0, a0 * b1); pL[1] = cvt_pk_bf16(a0 * b2, a0 * b3);
    pL[2] = cvt_pk_bf16(a1 * b0, a1 * b1); pL[3] = cvt_pk_bf16(a1 * b2, a1 * b3);
    pH[0] = cvt_pk_bf16(a2 * b0, a2 * b1); pH[1] = cvt_pk_bf16(a2 * b2, a2 * b3);
    pH[2] = cvt_pk_bf16(a3 * b0, a3 * b1); pH[3] = cvt_pk_bf16(a3 * b2, a3 * b3);

    f32x16 zacc;
    #pragma unroll
    for (int i = 0; i < 16; ++i) zacc[i] = 0.f;

    #pragma unroll
    for (int T = 0; T < 2; ++T) {
        // ---- B fragment: B[k=hi*8+i][patch=l31] = psi_{tile patch l31}[k] ----
        // Tile 0 patches 0..31: hi=0 lanes own pL; hi=1 lanes pull pH from lane-32.
        // Tile 1 patches 32..63: hi=1 lanes own pH; hi=0 lanes pull pL from lane+32.
        union { unsigned u[4]; bf16x8 v; } pb;
        #pragma unroll
        for (int c = 0; c < 4; ++c) {
            if (T == 0) {
                const unsigned sw = (unsigned)__shfl_xor((int)pH[c], 32, 64);
                pb.u[c] = hi ? sw : pL[c];
            } else {
                const unsigned sw = (unsigned)__shfl_xor((int)pL[c], 32, 64);
                pb.u[c] = hi ? pH[c] : sw;
            }
        }

        const f32x16 d = __builtin_amdgcn_mfma_f32_32x32x16_bf16(ua.v, pb.v, zacc, 0, 0, 0);

        // P_r = Re^2 + Im^2; reg r -> j = (r&3) + 8*(r>>2) + 4*hi (regs 8..15 = Im)
        float P[8];
        #pragma unroll
        for (int r = 0; r < 8; ++r) P[r] = fmaf(d[r], d[r], d[r + 8] * d[r + 8]);

        // 8-point Walsh over in-register j bits {j0,j1,j3}; j2 = hi (cross-lane).
        const float u0 = P[0] + P[1], u1 = P[0] - P[1];
        const float u2 = P[2] + P[3], u3 = P[2] - P[3];
        const float v0 = P[4] + P[5], v1 = P[4] - P[5];
        const float v2 = P[6] + P[7], v3 = P[6] - P[7];
        const float tpp0 = u0 + u2, tb1_0 = u0 - u2, tb0_0 = u1 + u3;
        const float tpp1 = v0 + v2, tb1_1 = v0 - v2, tb0_1 = v1 + v3;
        const float S   = tpp0 + tpp1;   // sum over lane's 8 j's
        const float z0p = tpp0 - tpp1;   // sign by j3 -> wire0
        const float z2p = tb1_0 + tb1_1; // sign by j1 -> wire2
        const float z3p = tb0_0 + tb0_1; // sign by j0 -> wire3
        const float Sx = __shfl_xor(S, 32, 64);
        const float z0 = z0p + __shfl_xor(z0p, 32, 64);
        const float z2 = z2p + __shfl_xor(z2p, 32, 64);
        const float z3 = z3p + __shfl_xor(z3p, 32, 64);
        const float z1 = hi ? (Sx - S) : (S - Sx);  // sign by j2 -> wire1

        if (!hi) {
            const int sp = wv * 64 + T * 32 + l31;
            if (sp < 196) sfeat4[sp] = make_float4(z0, z1, z2, z3);
        }
    }
    __syncthreads();

    // ---------- head: wave wv owns classes [cs, cs+nc) (R6-verified) ----------
    const float* sfeat = (const float*)sfeat4;
    const int cs = (wv == 0) ? 0 : (wv == 1) ? 3 : (wv == 2) ? 6 : 8;
    const int nc = (wv <= 1) ? 3 : 2;
    float acc0 = 0.f, acc1 = 0.f, acc2 = 0.f;
    #pragma unroll
    for (int i = 0; i < 12; ++i) {
        const int f = i * 64 + lane;
        const float fv = sfeat[f];
        acc0 = fmaf(W[(cs + 0) * 784 + f], fv, acc0);
        acc1 = fmaf(W[(cs + 1) * 784 + f], fv, acc1);
        if (nc > 2) acc2 = fmaf(W[(cs + 2) * 784 + f], fv, acc2);
    }
    if (lane < 16) {
        const int f = 768 + lane;
        const float fv = sfeat[f];
        acc0 = fmaf(W[(cs + 0) * 784 + f], fv, acc0);
        acc1 = fmaf(W[(cs + 1) * 784 + f], fv, acc1);
        if (nc > 2) acc2 = fmaf(W[(cs + 2) * 784 + f], fv, acc2);
    }
    #pragma unroll
    for (int off = 32; off; off >>= 1) {
        acc0 += __shfl_xor(acc0, off, 64);
        acc1 += __shfl_xor(acc1, off, 64);
        acc2 += __shfl_xor(acc2, off, 64);
    }
    if (lane == 0) {
        slog[cs + 0] = acc0 + bias[cs + 0];
        slog[cs + 1] = acc1 + bias[cs + 1];
        if (nc > 2) slog[cs + 2] = acc2 + bias[cs + 2];
    }
    __syncthreads();

    // ---------- softmax: lanes 0..15 of wave 0 (10 real) ----------
    if (wv == 0 && lane < 16) {
        const float lg = (lane < 10) ? slog[lane] : -1e30f;
        float m = lg;
        #pragma unroll
        for (int off = 8; off; off >>= 1) m = fmaxf(m, __shfl_xor(m, off, 64));
        float e = (lane < 10) ? __expf(lg - m) : 0.f;
        float s = e;
        #pragma unroll
        for (int off = 8; off; off >>= 1) s += __shfl_xor(s, off, 64);
        if (lane < 10) out[(size_t)img * 10 + lane] = lg - m - __logf(s);
    }
}

extern "C" void kernel_launch(void* const* d_in, const int* in_sizes, int n_in,
                              void* d_out, int out_size, void* d_ws, size_t ws_size,
                              hipStream_t stream) {
    const float* x    = (const float*)d_in[0];
    const float* U_re = (const float*)d_in[1];
    const float* U_im = (const float*)d_in[2];
    const float* W    = (const float*)d_in[3];
    const float* bias = (const float*)d_in[4];
    float* out = (float*)d_out;
    const int n = in_sizes[0] / 784;  // 4096 images
    quanv_one<<<n, 256, 0, stream>>>(x, U_re, U_im, W, bias, out);
}

// Round 8
// 17.087 us; speedup vs baseline: 1.6435x; 1.0711x over previous
//
#include <hip/hip_runtime.h>
#include <math.h>

using bf16x8 = __attribute__((ext_vector_type(8))) short;   // 8 bf16 in 4 VGPRs
using f32x16 = __attribute__((ext_vector_type(16))) float;  // 32x32 MFMA acc

static __device__ __forceinline__ unsigned cvt_pk_bf16(float lo, float hi) {
    unsigned r;
    asm("v_cvt_pk_bf16_f32 %0, %1, %2" : "=v"(r) : "v"(lo), "v"(hi));
    return r;
}

#define REV_HALF 0.07957747154594767f  // 1/(4*pi): theta -> revolutions of theta/2

// One block = one image; 4 waves; wave wv owns patches [wv*64, wv*64+64).
// Patch phase (R7-verified): per-lane psi (bf16 halves) -> shfl redistribution ->
// ONE mfma_f32_32x32x16_bf16 per 32-patch tile with A=[U_re;U_im] stacked (32x16,
// K exact) -> P=Re^2+Im^2 in-register -> 8-point Walsh (j2=hi cross-lane) -> z.
// Head phase: float4-vectorized W and sfeat reads; wave wv owns 2-3 classes;
// butterfly reduce; wave-0 parallel softmax.
__global__ __launch_bounds__(256) void quanv_one(
    const float* __restrict__ x,      // [N,1,28,28]
    const float* __restrict__ U_re,   // [16,16]
    const float* __restrict__ U_im,   // [16,16]
    const float* __restrict__ W,      // [10,784]
    const float* __restrict__ bias,   // [10]
    float* __restrict__ out)          // [N,10]
{
    __shared__ float4 sfeat4[196];    // z per patch
    __shared__ float  slog[10];

    const int tid  = threadIdx.x;
    const int wv   = tid >> 6;
    const int lane = tid & 63;
    const int l31  = lane & 31;
    const int hi   = lane >> 5;       // k-half / j2 bit
    const int img  = blockIdx.x;

    // ---- A fragment: stacked 32x16 [U_re; U_im]; row=lane&31, k=hi*8+i ----
    const float* Urow = (l31 < 16) ? (U_re + l31 * 16) : (U_im + (l31 - 16) * 16);
    const float4 uf0 = *(const float4*)(Urow + hi * 8);
    const float4 uf1 = *(const float4*)(Urow + hi * 8 + 4);
    union { unsigned u[4]; bf16x8 v; } ua;
    ua.u[0] = cvt_pk_bf16(uf0.x, uf0.y);
    ua.u[1] = cvt_pk_bf16(uf0.z, uf0.w);
    ua.u[2] = cvt_pk_bf16(uf1.x, uf1.y);
    ua.u[3] = cvt_pk_bf16(uf1.z, uf1.w);

    // ---- psi for this lane's own patch (clamped for slots >= 196) ----
    const int p   = (tid < 196) ? tid : 195;
    const int prw = p / 14;
    const int pcl = p - prw * 14;
    const float* xi = x + (size_t)img * 784 + prw * 56 + pcl * 2;
    const float2 t0 = *(const float2*)xi;
    const float2 t1 = *(const float2*)(xi + 28);
    const float r0 = t0.x * REV_HALF, r1 = t0.y * REV_HALF;
    const float r2 = t1.x * REV_HALF, r3 = t1.y * REV_HALF;
    const float s0 = __builtin_amdgcn_sinf(r0), c0 = __builtin_amdgcn_cosf(r0);
    const float s1 = __builtin_amdgcn_sinf(r1), c1 = __builtin_amdgcn_cosf(r1);
    const float s2 = __builtin_amdgcn_sinf(r2), c2 = __builtin_amdgcn_cosf(r2);
    const float s3 = __builtin_amdgcn_sinf(r3), c3 = __builtin_amdgcn_cosf(r3);
    const float a0 = c0 * c1, a1 = c0 * s1, a2 = s0 * c1, a3 = s0 * s1;
    const float b0 = c2 * c3, b1 = c2 * s3, b2 = s2 * c3, b3 = s2 * s3;

    // psi halves: pL = k0..7, pH = k8..15 (bf16 pairs)
    unsigned pL[4], pH[4];
    pL[0] = cvt_pk_bf16(a0 * b0, a0 * b1); pL[1] = cvt_pk_bf16(a0 * b2, a0 * b3);
    pL[2] = cvt_pk_bf16(a1 * b0, a1 * b1); pL[3] = cvt_pk_bf16(a1 * b2, a1 * b3);
    pH[0] = cvt_pk_bf16(a2 * b0, a2 * b1); pH[1] = cvt_pk_bf16(a2 * b2, a2 * b3);
    pH[2] = cvt_pk_bf16(a3 * b0, a3 * b1); pH[3] = cvt_pk_bf16(a3 * b2, a3 * b3);

    f32x16 zacc;
    #pragma unroll
    for (int i = 0; i < 16; ++i) zacc[i] = 0.f;

    #pragma unroll
    for (int T = 0; T < 2; ++T) {
        // ---- B fragment: B[k=hi*8+i][patch=l31] = psi_{tile patch l31}[k] ----
        union { unsigned u[4]; bf16x8 v; } pb;
        #pragma unroll
        for (int c = 0; c < 4; ++c) {
            if (T == 0) {
                const unsigned sw = (unsigned)__shfl_xor((int)pH[c], 32, 64);
                pb.u[c] = hi ? sw : pL[c];
            } else {
                const unsigned sw = (unsigned)__shfl_xor((int)pL[c], 32, 64);
                pb.u[c] = hi ? pH[c] : sw;
            }
        }

        const f32x16 d = __builtin_amdgcn_mfma_f32_32x32x16_bf16(ua.v, pb.v, zacc, 0, 0, 0);

        // P_r = Re^2 + Im^2; reg r -> j = (r&3) + 8*(r>>2) + 4*hi (regs 8..15 = Im)
        float P[8];
        #pragma unroll
        for (int r = 0; r < 8; ++r) P[r] = fmaf(d[r], d[r], d[r + 8] * d[r + 8]);

        // 8-point Walsh over in-register j bits {j0,j1,j3}; j2 = hi (cross-lane).
        const float u0 = P[0] + P[1], u1 = P[0] - P[1];
        const float u2 = P[2] + P[3], u3 = P[2] - P[3];
        const float v0 = P[4] + P[5], v1 = P[4] - P[5];
        const float v2 = P[6] + P[7], v3 = P[6] - P[7];
        const float tpp0 = u0 + u2, tb1_0 = u0 - u2, tb0_0 = u1 + u3;
        const float tpp1 = v0 + v2, tb1_1 = v0 - v2, tb0_1 = v1 + v3;
        const float S   = tpp0 + tpp1;   // sum over lane's 8 j's
        const float z0p = tpp0 - tpp1;   // sign by j3 -> wire0
        const float z2p = tb1_0 + tb1_1; // sign by j1 -> wire2
        const float z3p = tb0_0 + tb0_1; // sign by j0 -> wire3
        const float Sx = __shfl_xor(S, 32, 64);
        const float z0 = z0p + __shfl_xor(z0p, 32, 64);
        const float z2 = z2p + __shfl_xor(z2p, 32, 64);
        const float z3 = z3p + __shfl_xor(z3p, 32, 64);
        const float z1 = hi ? (Sx - S) : (S - Sx);  // sign by j2 -> wire1

        if (!hi) {
            const int sp = wv * 64 + T * 32 + l31;
            if (sp < 196) sfeat4[sp] = make_float4(z0, z1, z2, z3);
        }
    }
    __syncthreads();

    // ---------- head: wave wv owns classes [cs, cs+nc); float4-vectorized ----------
    const int cs = (wv == 0) ? 0 : (wv == 1) ? 3 : (wv == 2) ? 6 : 8;
    const int nc = (wv <= 1) ? 3 : 2;
    float acc0 = 0.f, acc1 = 0.f, acc2 = 0.f;
    #pragma unroll
    for (int i = 0; i < 4; ++i) {
        const int q = i * 64 + lane;        // float4 group index, 0..195
        if (q < 196) {
            const float4 fv = sfeat4[q];
            const float4 w0 = *(const float4*)(W + (cs + 0) * 784 + q * 4);
            const float4 w1 = *(const float4*)(W + (cs + 1) * 784 + q * 4);
            acc0 = fmaf(w0.x, fv.x, fmaf(w0.y, fv.y, fmaf(w0.z, fv.z, fmaf(w0.w, fv.w, acc0))));
            acc1 = fmaf(w1.x, fv.x, fmaf(w1.y, fv.y, fmaf(w1.z, fv.z, fmaf(w1.w, fv.w, acc1))));
            if (nc > 2) {
                const float4 w2 = *(const float4*)(W + (cs + 2) * 784 + q * 4);
                acc2 = fmaf(w2.x, fv.x, fmaf(w2.y, fv.y, fmaf(w2.z, fv.z, fmaf(w2.w, fv.w, acc2))));
            }
        }
    }
    #pragma unroll
    for (int off = 32; off; off >>= 1) {
        acc0 += __shfl_xor(acc0, off, 64);
        acc1 += __shfl_xor(acc1, off, 64);
        acc2 += __shfl_xor(acc2, off, 64);
    }
    if (lane == 0) {
        slog[cs + 0] = acc0 + bias[cs + 0];
        slog[cs + 1] = acc1 + bias[cs + 1];
        if (nc > 2) slog[cs + 2] = acc2 + bias[cs + 2];
    }
    __syncthreads();

    // ---------- softmax: lanes 0..15 of wave 0 (10 real) ----------
    if (wv == 0 && lane < 16) {
        const float lg = (lane < 10) ? slog[lane] : -1e30f;
        float m = lg;
        #pragma unroll
        for (int off = 8; off; off >>= 1) m = fmaxf(m, __shfl_xor(m, off, 64));
        float e = (lane < 10) ? __expf(lg - m) : 0.f;
        float s = e;
        #pragma unroll
        for (int off = 8; off; off >>= 1) s += __shfl_xor(s, off, 64);
        if (lane < 10) out[(size_t)img * 10 + lane] = lg - m - __logf(s);
    }
}

extern "C" void kernel_launch(void* const* d_in, const int* in_sizes, int n_in,
                              void* d_out, int out_size, void* d_ws, size_t ws_size,
                              hipStream_t stream) {
    const float* x    = (const float*)d_in[0];
    const float* U_re = (const float*)d_in[1];
    const float* U_im = (const float*)d_in[2];
    const float* W    = (const float*)d_in[3];
    const float* bias = (const float*)d_in[4];
    float* out = (float*)d_out;
    const int n = in_sizes[0] / 784;  // 4096 images
    quanv_one<<<n, 256, 0, stream>>>(x, U_re, U_im, W, bias, out);
}